// Round 6
// baseline (151.548 us; speedup 1.0000x reference)
//
#include <hip/hip_runtime.h>

// CapsuleLinear dynamic routing via bf16 hi/lo MFMA (round-4 numerics,
// round-5 pipelining). N=64, I=256, O=128, K=16, L=32, 3 iters.
//
// caps_prep: w,x fp32 -> bf16 hi + bf16 lo residual, pre-swizzled into
//   v_mfma_f32_32x32x16_bf16 fragment order, hi/lo interleaved as one 32B
//   record per (tile,lane): [ah 16B | al 16B].
// caps_main: grid 256 = (o 0..127) x (n-half 0..1), 512 thr, 8 waves x 32 i.
//   Per i: 3 MFMAs (al*bh + ah*bl + ah*bh ~= fp32 product, err ~2^-17).
//   2-i batches, double-buffered register prefetch (8 x 16B loads in flight).
//   Fused 3-pass routing (no-max softmax, logits in LDS [i][n]):
//   P0: s0 = (1/256) sum_i P_i (pure MFMA chains)
//   P1: d=P_i.v0 -> lg, e=exp(d), u+=e*P_i, z+=e -> s1
//   P2: same with d+=lg -> s2 -> squash -> out
// Fallback (ws too small): round-3 VALU kernel.

#define ICAPS 256
#define OCAPS 128
#define WS_WC 0ull
#define WS_XC 67108864ull
#define WS_NEED 68157440ull

typedef __attribute__((ext_vector_type(8))) short s16x8;
typedef __attribute__((ext_vector_type(16))) float f32x16;

__device__ inline unsigned bfbits(float f) {   // RNE bf16, as fp32 bit pattern
    unsigned u = __float_as_uint(f);
    return (u + 0x7FFFu + ((u >> 16) & 1u)) & 0xFFFF0000u;
}

// ---------------- prep: fp32 -> bf16 hi/lo interleaved fragments ----------------
__global__ __launch_bounds__(512)
void caps_prep(const float* __restrict__ x, const float* __restrict__ w,
               unsigned char* __restrict__ ws) {
    const int wv = threadIdx.x >> 6, lane = threadIdx.x & 63;
    uint4* WC = (uint4*)(ws + WS_WC);
    uint4* XC = (uint4*)(ws + WS_XC);
    const int gid = blockIdx.x * 8 + wv;

    float f[8];
    if (gid < 32768) {                 // w tile: gid = o*256 + i
        const int l = lane & 31, kb = (lane >> 5) * 8;
        const float* src = w + ((size_t)gid * 16 + kb) * 32 + l;
        #pragma unroll
        for (int j = 0; j < 8; ++j) f[j] = src[j * 32];
        unsigned h[4], g[4];
        #pragma unroll
        for (int c = 0; c < 4; ++c) {
            unsigned b0 = bfbits(f[2 * c]), b1 = bfbits(f[2 * c + 1]);
            h[c] = (b0 >> 16) | (b1 & 0xFFFF0000u);
            float l0 = f[2 * c] - __uint_as_float(b0);
            float l1 = f[2 * c + 1] - __uint_as_float(b1);
            g[c] = (bfbits(l0) >> 16) | (bfbits(l1) & 0xFFFF0000u);
        }
        const size_t idx = ((size_t)gid * 64 + lane) * 2;
        WC[idx]     = make_uint4(h[0], h[1], h[2], h[3]);
        WC[idx + 1] = make_uint4(g[0], g[1], g[2], g[3]);
    } else {                           // x tile: gid-32768 = nh*256 + i
        const int id = gid - 32768;
        const int nh = id >> 8, i = id & 255;
        const int np = lane & 31, kb = (lane >> 5) * 8;
        const float* src = x + ((size_t)(nh * 32 + np) * ICAPS + i) * 16 + kb;
        const float4 a = *(const float4*)src;
        const float4 b = *(const float4*)(src + 4);
        f[0] = a.x; f[1] = a.y; f[2] = a.z; f[3] = a.w;
        f[4] = b.x; f[5] = b.y; f[6] = b.z; f[7] = b.w;
        unsigned h[4], g[4];
        #pragma unroll
        for (int c = 0; c < 4; ++c) {
            unsigned b0 = bfbits(f[2 * c]), b1 = bfbits(f[2 * c + 1]);
            h[c] = (b0 >> 16) | (b1 & 0xFFFF0000u);
            float l0 = f[2 * c] - __uint_as_float(b0);
            float l1 = f[2 * c + 1] - __uint_as_float(b1);
            g[c] = (bfbits(l0) >> 16) | (bfbits(l1) & 0xFFFF0000u);
        }
        const size_t idx = ((size_t)id * 64 + lane) * 2;
        XC[idx]     = make_uint4(h[0], h[1], h[2], h[3]);
        XC[idx + 1] = make_uint4(g[0], g[1], g[2], g[3]);
    }
}

// ---------------- main: MFMA routing ----------------
__global__ __launch_bounds__(512)
void caps_main(const unsigned char* __restrict__ ws, float* __restrict__ out) {
    __shared__ float lg[ICAPS * 32];      // [i][n] 32 KB
    __shared__ float slab[8 * 1280];      // per-wave u partials (lane stride 20)
    __shared__ float svv[32 * 33];        // s then v
    __shared__ float zz[8 * 32];
    __shared__ float zinv[32];

    const int t = threadIdx.x, wv = t >> 6, lane = t & 63;
    const int o = blockIdx.x & 127, nh = blockIdx.x >> 7;   // o-pairs share an XCD
    const int n = lane & 31, half = lane >> 5;

    // per (i,lane): 2 consecutive s16x8 records (hi, lo); stride per i = 128
    const s16x8* Wp = (const s16x8*)(ws + WS_WC) + ((size_t)o * ICAPS * 64 + lane) * 2;
    const s16x8* Xp = (const s16x8*)(ws + WS_XC) + ((size_t)nh * ICAPS * 64 + lane) * 2;

    float vr[16];
    const int ibase = wv * 32;

    for (int pass = 0; pass < 3; ++pass) {
        float uacc[16];
        #pragma unroll
        for (int r = 0; r < 16; ++r) uacc[r] = 0.f;
        float z = 0.f;

        // cur/nxt register buffers for a 2-i batch: [ah al bh bl] x 2
        s16x8 C[8], Nx[8];
        {
            const size_t b0 = (size_t)ibase * 128;
            C[0] = Wp[b0];       C[1] = Wp[b0 + 1];
            C[2] = Xp[b0];       C[3] = Xp[b0 + 1];
            C[4] = Wp[b0 + 128]; C[5] = Wp[b0 + 129];
            C[6] = Xp[b0 + 128]; C[7] = Xp[b0 + 129];
        }

        if (pass == 0) {
            f32x16 Pa = {}, Pb = {};
            for (int bb = 0; bb < 16; ++bb) {
                if (bb < 15) {
                    const size_t bn = (size_t)(ibase + 2 * (bb + 1)) * 128;
                    Nx[0] = Wp[bn];       Nx[1] = Wp[bn + 1];
                    Nx[2] = Xp[bn];       Nx[3] = Xp[bn + 1];
                    Nx[4] = Wp[bn + 128]; Nx[5] = Wp[bn + 129];
                    Nx[6] = Xp[bn + 128]; Nx[7] = Xp[bn + 129];
                }
                Pa = __builtin_amdgcn_mfma_f32_32x32x16_bf16(C[1], C[2], Pa, 0, 0, 0);
                Pb = __builtin_amdgcn_mfma_f32_32x32x16_bf16(C[5], C[6], Pb, 0, 0, 0);
                Pa = __builtin_amdgcn_mfma_f32_32x32x16_bf16(C[0], C[3], Pa, 0, 0, 0);
                Pb = __builtin_amdgcn_mfma_f32_32x32x16_bf16(C[4], C[7], Pb, 0, 0, 0);
                Pa = __builtin_amdgcn_mfma_f32_32x32x16_bf16(C[0], C[2], Pa, 0, 0, 0);
                Pb = __builtin_amdgcn_mfma_f32_32x32x16_bf16(C[4], C[6], Pb, 0, 0, 0);
                if (bb < 15) {
                    #pragma unroll
                    for (int j = 0; j < 8; ++j) C[j] = Nx[j];
                }
            }
            #pragma unroll
            for (int r = 0; r < 16; ++r) uacc[r] = Pa[r] + Pb[r];
        } else {
            for (int bb = 0; bb < 16; ++bb) {
                if (bb < 15) {
                    const size_t bn = (size_t)(ibase + 2 * (bb + 1)) * 128;
                    Nx[0] = Wp[bn];       Nx[1] = Wp[bn + 1];
                    Nx[2] = Xp[bn];       Nx[3] = Xp[bn + 1];
                    Nx[4] = Wp[bn + 128]; Nx[5] = Wp[bn + 129];
                    Nx[6] = Xp[bn + 128]; Nx[7] = Xp[bn + 129];
                }
                f32x16 P0 = {}, P1 = {};
                P0 = __builtin_amdgcn_mfma_f32_32x32x16_bf16(C[1], C[2], P0, 0, 0, 0);
                P1 = __builtin_amdgcn_mfma_f32_32x32x16_bf16(C[5], C[6], P1, 0, 0, 0);
                P0 = __builtin_amdgcn_mfma_f32_32x32x16_bf16(C[0], C[3], P0, 0, 0, 0);
                P1 = __builtin_amdgcn_mfma_f32_32x32x16_bf16(C[4], C[7], P1, 0, 0, 0);
                P0 = __builtin_amdgcn_mfma_f32_32x32x16_bf16(C[0], C[2], P0, 0, 0, 0);
                P1 = __builtin_amdgcn_mfma_f32_32x32x16_bf16(C[4], C[6], P1, 0, 0, 0);

                #pragma unroll
                for (int j = 0; j < 2; ++j) {
                    const f32x16& P = j ? P1 : P0;
                    const int i = ibase + bb * 2 + j;
                    float da = P[0] * vr[0];
                    float db = P[8] * vr[8];
                    #pragma unroll
                    for (int r = 1; r < 8; ++r) {
                        da = fmaf(P[r], vr[r], da);
                        db = fmaf(P[r + 8], vr[r + 8], db);
                    }
                    float d = da + db;
                    d += __shfl_xor(d, 32);                 // combine l-halves
                    if (pass == 1) {
                        if (half == 0) lg[i * 32 + n] = d;  // store logits for pass 2
                    } else {
                        d += lg[i * 32 + n];
                    }
                    const float e = __expf(d);
                    z += e;
                    #pragma unroll
                    for (int r = 0; r < 16; ++r) uacc[r] = fmaf(e, P[r], uacc[r]);
                }
                if (bb < 15) {
                    #pragma unroll
                    for (int j = 0; j < 8; ++j) C[j] = Nx[j];
                }
            }
        }

        // ---- cross-wave reduce of u (and z) ----
        #pragma unroll
        for (int c = 0; c < 4; ++c)
            *(float4*)(&slab[wv * 1280 + lane * 20 + c * 4]) =
                make_float4(uacc[4 * c], uacc[4 * c + 1], uacc[4 * c + 2], uacc[4 * c + 3]);
        if (pass > 0 && half == 0) zz[wv * 32 + n] = z;
        __syncthreads();

        #pragma unroll
        for (int hh = 0; hh < 2; ++hh) {
            const int e = t + hh * 512;
            const int lw = e >> 4, r = e & 15;
            float s = 0.f;
            #pragma unroll
            for (int w8 = 0; w8 < 8; ++w8) s += slab[w8 * 1280 + lw * 20 + r];
            const int nn = lw & 31, ll = (r & 3) + 8 * (r >> 2) + 4 * (lw >> 5);
            svv[nn * 33 + ll] = s;
        }
        if (t < 32) {
            if (pass == 0) zinv[t] = 1.0f / 256.0f;
            else {
                float zs = 0.f;
                #pragma unroll
                for (int w8 = 0; w8 < 8; ++w8) zs += zz[w8 * 32 + t];
                zinv[t] = 1.0f / zs;
            }
        }
        __syncthreads();

        // ---- squash (and output on last pass) ----
        {
            const int nq = t >> 4, sub = t & 15;
            const float a = svv[nq * 33 + sub] * zinv[nq];
            const float b = svv[nq * 33 + sub + 16] * zinv[nq];
            float sq = a * a + b * b;
            #pragma unroll
            for (int m = 1; m < 16; m <<= 1) sq += __shfl_xor(sq, m, 16);
            const float sc = sqrtf(sq) / (1.0f + sq);
            if (pass == 2) {
                const int ng = nh * 32 + nq;
                out[((size_t)ng * OCAPS + o) * 32 + sub] = a * sc;
                out[((size_t)ng * OCAPS + o) * 32 + sub + 16] = b * sc;
            } else {
                svv[nq * 33 + sub] = a * sc;
                svv[nq * 33 + sub + 16] = b * sc;
            }
        }
        if (pass < 2) {
            __syncthreads();
            #pragma unroll
            for (int r = 0; r < 16; ++r) {
                const int l = (r & 3) + 8 * (r >> 2) + 4 * half;
                vr[r] = svv[n * 33 + l];
            }
        }
    }
}

// ---------------- fallback (round-3 kernel, no ws needed) ----------------
#define KLEN  16
#define LLEN  32
#define TN    16
#define LGS   257
#define XROW  20
#define XIST  (TN * XROW + 4)
#define SVS   33
#define RBS   33
#define NSTG  32
#define NSTEP (ICAPS / NSTG)

__global__ __launch_bounds__(512, 2)
void caps_route_fb(const float* __restrict__ xg_all,
                   const float* __restrict__ wg_all,
                   float* __restrict__ out) {
    __shared__ float lg[TN * LGS];
    __shared__ float xt[NSTG * XIST];
    __shared__ float sv[TN * SVS];
    __shared__ float zz[8][TN];
    __shared__ float zinv[TN];

    const int t   = threadIdx.x;
    const int o   = blockIdx.x & 127;
    const int n0  = (blockIdx.x >> 7) * TN;
    const int isp = t >> 4;
    const int lb  = (t >> 2) & 3;
    const int nb  = t & 3;
    const int l0  = lb * 8;

    const float* xg = xg_all + (size_t)n0 * ICAPS * KLEN;
    const float* wg = wg_all + (size_t)o * ICAPS * KLEN * LLEN;

    for (int pass = 0; pass < 3; ++pass) {
        float u[4][8];
        float zq[4] = {0.f, 0.f, 0.f, 0.f};
        #pragma unroll
        for (int q = 0; q < 4; ++q)
            #pragma unroll
            for (int r = 0; r < 8; ++r) u[q][r] = 0.f;

        for (int st = 0; st < NSTEP; ++st) {
            const int i0 = st * NSTG;
            __syncthreads();
            #pragma unroll
            for (int j = 0; j < 4; ++j) {
                const int g   = j * 512 + t;
                const int nn  = g >> 7;
                const int rem = g & 127;
                const int il  = rem >> 2;
                const int k4c = rem & 3;
                *(float4*)(&xt[il * XIST + nn * XROW + k4c * 4]) =
                    *(const float4*)(xg + (size_t)(nn * ICAPS + i0 + il) * KLEN + k4c * 4);
            }
            __syncthreads();

            const int i = i0 + isp;
            const float* wp = wg + (size_t)i * (KLEN * LLEN) + l0;
            const float* xp = &xt[isp * XIST];
            float P[4][8];
            #pragma unroll
            for (int q = 0; q < 4; ++q)
                #pragma unroll
                for (int r = 0; r < 8; ++r) P[q][r] = 0.f;

            #pragma unroll
            for (int k4 = 0; k4 < 4; ++k4) {
                float xq[4][4];
                #pragma unroll
                for (int q = 0; q < 4; ++q)
                    *(float4*)(&xq[q][0]) = *(const float4*)(xp + (nb + 4 * q) * XROW + k4 * 4);
                #pragma unroll
                for (int kk = 0; kk < 4; ++kk) {
                    const int k = k4 * 4 + kk;
                    const float4 wa = *(const float4*)(wp + k * LLEN);
                    const float4 wb = *(const float4*)(wp + k * LLEN + 4);
                    #pragma unroll
                    for (int q = 0; q < 4; ++q) {
                        const float xv = xq[q][kk];
                        P[q][0] = fmaf(xv, wa.x, P[q][0]);
                        P[q][1] = fmaf(xv, wa.y, P[q][1]);
                        P[q][2] = fmaf(xv, wa.z, P[q][2]);
                        P[q][3] = fmaf(xv, wa.w, P[q][3]);
                        P[q][4] = fmaf(xv, wb.x, P[q][4]);
                        P[q][5] = fmaf(xv, wb.y, P[q][5]);
                        P[q][6] = fmaf(xv, wb.z, P[q][6]);
                        P[q][7] = fmaf(xv, wb.w, P[q][7]);
                    }
                }
            }

            if (pass == 0) {
                #pragma unroll
                for (int q = 0; q < 4; ++q)
                    #pragma unroll
                    for (int r = 0; r < 8; ++r) u[q][r] += P[q][r];
            } else {
                #pragma unroll
                for (int q = 0; q < 4; ++q) {
                    const float* vp = &sv[(nb + 4 * q) * SVS + l0];
                    float d = P[q][0] * vp[0] + P[q][1] * vp[1] + P[q][2] * vp[2] + P[q][3] * vp[3]
                            + P[q][4] * vp[4] + P[q][5] * vp[5] + P[q][6] * vp[6] + P[q][7] * vp[7];
                    d += __shfl_xor(d, 4);
                    d += __shfl_xor(d, 8);
                    float lnew = d;
                    if (pass == 2) lnew += lg[(nb + 4 * q) * LGS + i];
                    else if (lb == 0) lg[(nb + 4 * q) * LGS + i] = lnew;
                    const float e = __expf(lnew);
                    zq[q] += e;
                    #pragma unroll
                    for (int r = 0; r < 8; ++r) u[q][r] = fmaf(e, P[q][r], u[q][r]);
                }
            }
        }

        #pragma unroll
        for (int q = 0; q < 4; ++q) {
            #pragma unroll
            for (int r = 0; r < 8; ++r) {
                float v = u[q][r];
                v += __shfl_xor(v, 16);
                v += __shfl_xor(v, 32);
                u[q][r] = v;
            }
            float zv = zq[q];
            zv += __shfl_xor(zv, 16);
            zv += __shfl_xor(zv, 32);
            zq[q] = zv;
        }
        __syncthreads();
        {
            const int wvv = t >> 6, lane = t & 63;
            if (lane < 16) {
                float* rb = &xt[wvv * (16 * RBS) + lane * RBS];
                #pragma unroll
                for (int q = 0; q < 4; ++q)
                    #pragma unroll
                    for (int r = 0; r < 8; ++r) rb[q * 8 + r] = u[q][r];
            }
            if (pass > 0 && lane < 4) {
                #pragma unroll
                for (int q = 0; q < 4; ++q) zz[wvv][lane + 4 * q] = zq[q];
            }
        }
        __syncthreads();
        {
            const int low4 = t >> 5, qr = t & 31;
            const int qq = qr >> 3, rr = qr & 7;
            const int lbb = low4 >> 2, nbb = low4 & 3;
            float ssum = 0.f;
            #pragma unroll
            for (int w8 = 0; w8 < 8; ++w8) ssum += xt[w8 * (16 * RBS) + low4 * RBS + qr];
            sv[(nbb + 4 * qq) * SVS + lbb * 8 + rr] = ssum;
        }
        if (t < TN) {
            if (pass == 0) zinv[t] = 1.0f / 256.0f;
            else {
                float zs = 0.f;
                #pragma unroll
                for (int w8 = 0; w8 < 8; ++w8) zs += zz[w8][t];
                zinv[t] = 1.0f / zs;
            }
        }
        __syncthreads();
        {
            const int nn = t >> 5, l = t & 31;
            const float val = sv[nn * SVS + l] * zinv[nn];
            float sq = val * val;
            #pragma unroll
            for (int m = 1; m < 32; m <<= 1) sq += __shfl_xor(sq, m, 32);
            const float sc = sqrtf(sq) / (1.0f + sq);
            if (pass == 2)
                out[((size_t)(n0 + nn) * OCAPS + o) * LLEN + l] = val * sc;
            else
                sv[nn * SVS + l] = val * sc;
        }
    }
}

extern "C" void kernel_launch(void* const* d_in, const int* in_sizes, int n_in,
                              void* d_out, int out_size, void* d_ws, size_t ws_size,
                              hipStream_t stream) {
    const float* x = (const float*)d_in[0];   // [64,256,16]
    const float* w = (const float*)d_in[1];   // [128,256,16,32]
    float* outp = (float*)d_out;              // [64,128,32]
    if (ws_size >= WS_NEED) {
        caps_prep<<<dim3(4160), dim3(512), 0, stream>>>(x, w, (unsigned char*)d_ws);
        caps_main<<<dim3(256), dim3(512), 0, stream>>>((const unsigned char*)d_ws, outp);
    } else {
        caps_route_fb<<<dim3(512), dim3(512), 0, stream>>>(x, w, outp);
    }
}